// Round 1
// 440.147 us; speedup vs baseline: 1.0592x; 1.0592x over previous
//
#include <hip/hip_runtime.h>

#define LOG2E 1.44269504088896340736f
#define QSCALE 0.18033688011112042f  // 0.125 * LOG2E

typedef __attribute__((ext_vector_type(8))) short bf16x8;
typedef __attribute__((ext_vector_type(4))) float f32x4;

__device__ __forceinline__ unsigned short f2b(float f) {
  union { float f; unsigned int u; } x; x.f = f;
  return (unsigned short)((x.u + 0x8000u) >> 16);
}

// pack two fp32 -> two bf16 in 3 VALU ops
__device__ __forceinline__ unsigned int pk_bf16(float a, float b) {
  union { float f; unsigned int u; } xa, xb; xa.f = a; xb.f = b;
  return __builtin_amdgcn_perm(xb.u + 0x8000u, xa.u + 0x8000u, 0x07060302);
}

__device__ __forceinline__ void gld_lds16(const void* g, void* l) {
  __builtin_amdgcn_global_load_lds((const __attribute__((address_space(1))) void*)g,
                                   (__attribute__((address_space(3))) void*)l,
                                   16, 0, 0);
}

// raw workgroup barrier (NO implicit vmcnt drain, unlike __syncthreads)
__device__ __forceinline__ void wgbar() {
  asm volatile("" ::: "memory");
  __builtin_amdgcn_s_barrier();
  asm volatile("" ::: "memory");
}
#define SWAIT(s) asm volatile("s_waitcnt " s ::: "memory")

// ---------------- fused cast x,y fp32 -> bf16 ----------------
__global__ __launch_bounds__(256) void cast_xy(const float* __restrict__ x,
                                               const float* __restrict__ y,
                                               unsigned short* __restrict__ xb,
                                               unsigned short* __restrict__ yb) {
  int i = blockIdx.x * 256 + threadIdx.x;
  const float* in = x; unsigned short* out = xb;
  if (i >= 2097152) { in = y; out = yb; i -= 2097152; }
  float4 v = ((const float4*)in)[i];
  uint2 o;
  o.x = pk_bf16(v.x, v.y);
  o.y = pk_bf16(v.z, v.w);
  ((uint2*)out)[i] = o;
}

// ---------------- mask pre-scale: out = mask * log2(e), fp32 ----------------
__global__ __launch_bounds__(256) void scale_mask(const float* __restrict__ in,
                                                  float* __restrict__ out) {
  int i = blockIdx.x * 256 + threadIdx.x;
  f32x4 v = ((const f32x4*)in)[i];
  ((f32x4*)out)[i] = v * LOG2E;
}

// ---------------- fused transpose+cast of Wkv, Wq, Wo ----------------
__global__ __launch_bounds__(256) void transpose_cast_all(
    const float* __restrict__ Wkv, const float* __restrict__ Wq,
    const float* __restrict__ Wo, unsigned short* __restrict__ wkvt,
    unsigned short* __restrict__ wqt, unsigned short* __restrict__ wot) {
  __shared__ float t[32][33];
  int tb = blockIdx.x;
  const float* W; unsigned short* Wt; int N;
  if (tb < 2048)      { W = Wkv; Wt = wkvt; N = 2048; }
  else if (tb < 3072) { W = Wq;  Wt = wqt;  N = 1024; tb -= 2048; }
  else                { W = Wo;  Wt = wot;  N = 1024; tb -= 3072; }
  const int K = 1024;
  int tilesN = N >> 5;
  int nb = (tb % tilesN) * 32, kb = (tb / tilesN) * 32;
  int j = threadIdx.x & 31, i0 = threadIdx.x >> 5;
  #pragma unroll
  for (int p = 0; p < 4; ++p) {
    int i = i0 + p * 8;
    t[i][j] = W[(size_t)(kb + i) * N + nb + j];
  }
  __syncthreads();
  #pragma unroll
  for (int p = 0; p < 4; ++p) {
    int i = i0 + p * 8;
    Wt[(size_t)(nb + i) * K + kb + j] = f2b(t[j][i]);
  }
}

// ---------------- GEMM: C(MxN) = A(MxK) @ Bt(NxK)^T + bias ----------------
// XOR-granule-swizzled LDS (conflict-free b128 fragment reads).
// MODE 0: fp32 C out. MODE 1: kv -> K[b,h,s,64] + Vt[b,h,64,s]. MODE 2: q -> Q * QSCALE.
template <int MODE>
__global__ __launch_bounds__(256)
void gemm128(const unsigned short* __restrict__ A,
             const unsigned short* __restrict__ Bt,
             const float* __restrict__ bias,
             void* __restrict__ out0, void* __restrict__ out1,
             int M, int N, int K) {
  __shared__ __align__(16) unsigned short As[128 * 64];
  __shared__ __align__(16) unsigned short Bs[128 * 64];
  const int tid = threadIdx.x;
  const int bn = blockIdx.x, bm = blockIdx.y;
  const int wave = tid >> 6, lane = tid & 63;
  const int wm = (wave >> 1) * 64, wn = (wave & 1) * 64;
  const int lrow = lane & 15, quad = lane >> 4;
  const int sw = lrow & 7;  // fragment-read granule swizzle

  f32x4 acc[4][4];
  #pragma unroll
  for (int i = 0; i < 4; ++i)
    #pragma unroll
    for (int j = 0; j < 4; ++j)
      #pragma unroll
      for (int r = 0; r < 4; ++r) acc[i][j][r] = 0.f;

  const unsigned short* Ab = A + (size_t)(bm * 128) * K;
  const unsigned short* Bb = Bt + (size_t)(bn * 128) * K;

  for (int k0 = 0; k0 < K; k0 += 64) {
    #pragma unroll
    for (int i = 0; i < 4; ++i) {
      int e = i * 256 + tid;
      int row = e >> 3, gs = (e & 7) ^ (row & 7);
      gld_lds16(Ab + (size_t)row * K + k0 + gs * 8, &As[e * 8]);
    }
    #pragma unroll
    for (int i = 0; i < 4; ++i) {
      int e = i * 256 + tid;
      int row = e >> 3, gs = (e & 7) ^ (row & 7);
      gld_lds16(Bb + (size_t)row * K + k0 + gs * 8, &Bs[e * 8]);
    }
    __builtin_amdgcn_s_waitcnt(0);
    __syncthreads();
    #pragma unroll
    for (int ks = 0; ks < 2; ++ks) {
      bf16x8 af[4], bf[4];
      const int g = ((ks * 4 + quad) ^ sw) * 8;
      #pragma unroll
      for (int i = 0; i < 4; ++i)
        af[i] = *(const bf16x8*)&As[(wm + i * 16 + lrow) * 64 + g];
      #pragma unroll
      for (int j = 0; j < 4; ++j)
        bf[j] = *(const bf16x8*)&Bs[(wn + j * 16 + lrow) * 64 + g];
      #pragma unroll
      for (int i = 0; i < 4; ++i)
        #pragma unroll
        for (int j = 0; j < 4; ++j)
          acc[i][j] = __builtin_amdgcn_mfma_f32_16x16x32_bf16(af[i], bf[j], acc[i][j], 0, 0, 0);
    }
    __syncthreads();
  }

  const int col0 = bn * 128 + wn;
  #pragma unroll
  for (int i = 0; i < 4; ++i) {
    const int row0 = bm * 128 + wm + i * 16 + quad * 4;
    const int b = row0 >> 11, s0 = row0 & 2047;
    #pragma unroll
    for (int j = 0; j < 4; ++j) {
      const int cc = j * 16 + lrow;
      const float bv = bias[col0 + cc];
      float v0 = acc[i][j][0] + bv, v1 = acc[i][j][1] + bv;
      float v2 = acc[i][j][2] + bv, v3 = acc[i][j][3] + bv;
      if (MODE == 0) {
        float* C = (float*)out0;
        size_t off = (size_t)row0 * N + col0 + cc;
        C[off] = v0; C[off + N] = v1; C[off + 2 * N] = v2; C[off + 3 * N] = v3;
      } else if (MODE == 1) {
        const int h = col0 >> 7;
        if ((col0 & 64) == 0) {  // K half: K[b,h,s,64]
          unsigned short* Kb = (unsigned short*)out0;
          size_t base = ((size_t)(b * 16 + h) * 2048 + s0) * 64 + cc;
          Kb[base] = f2b(v0); Kb[base + 64] = f2b(v1);
          Kb[base + 128] = f2b(v2); Kb[base + 192] = f2b(v3);
        } else {                 // V half: Vt[b,h,64,s]
          unsigned short* Vt = (unsigned short*)out1;
          size_t base = ((size_t)(b * 16 + h) * 64 + cc) * 2048 + s0;
          uint2 p; p.x = pk_bf16(v0, v1); p.y = pk_bf16(v2, v3);
          *(uint2*)&Vt[base] = p;
        }
      } else {  // MODE 2: Q[b,h,s,64] pre-scaled
        v0 *= QSCALE; v1 *= QSCALE; v2 *= QSCALE; v3 *= QSCALE;
        const int h = col0 >> 6;
        unsigned short* Qb = (unsigned short*)out0;
        size_t base = ((size_t)(b * 16 + h) * 2048 + s0) * 64 + cc;
        Qb[base] = f2b(v0); Qb[base + 64] = f2b(v1);
        Qb[base + 128] = f2b(v2); Qb[base + 192] = f2b(v3);
      }
    }
  }
}

// ---------------- flash attention v5: software-pipelined K/V staging --------
// grid 1024; 2 qt per XCD (mask L2-resident). 4 waves x 32 q-cols.
// Double-buffered K tile + late-issued single-buffered V tile; raw s_barrier
// with counted vmcnt (never drains to 0 in the loop). Ps is pitch-64 with the
// same 16B-granule XOR swizzle as Ks/Vs -> LDS = 40960 B = 4 blocks/CU.
__global__ __launch_bounds__(256, 4)
void attn(const unsigned short* __restrict__ Qbuf,
          const unsigned short* __restrict__ Kbuf,
          const unsigned short* __restrict__ Vtbuf,
          const float* __restrict__ masks,   // mask * log2e, fp32
          unsigned short* __restrict__ vals) {
  const int blk = blockIdx.x;
  const int xcd = blk & 7, slot = blk >> 3;       // slot 0..127
  const int qt = xcd * 2 + (slot >> 6);           // 2 qt values per XCD
  const int hb = slot & 63;
  const int b = hb >> 4, h = hb & 15;
  const int tid = threadIdx.x, lane = tid & 63, w = tid >> 6;
  const int lrow = lane & 15, quad = lane >> 4;
  const int sw = lrow & 7;

  __shared__ __align__(16) unsigned short Ks[2][64 * 64];  // [key][d] swizzled, dbuf
  __shared__ __align__(16) unsigned short Vs[64 * 64];     // [d][key] swizzled
  __shared__ __align__(16) unsigned short Ps[128 * 64];    // Q staging, then P (swizzled)

  const unsigned short* qp = Qbuf + ((size_t)(b * 16 + h) * 2048 + qt * 128) * 64;
  const unsigned short* kp = Kbuf + (size_t)(b * 16 + h) * 2048 * 64;
  const unsigned short* vp = Vtbuf + (size_t)(b * 16 + h) * 64 * 2048;
  const float* mp = masks + (size_t)(qt * 128 + w * 32) * 2048;

  // ---- prologue: stage Q (swizzled), K tile 0, V tile 0 ----
  #pragma unroll
  for (int i = 0; i < 4; ++i) {
    int e = i * 256 + tid;
    int row = e >> 3, gs = (e & 7) ^ (row & 7);
    gld_lds16(qp + (size_t)row * 64 + gs * 8, &Ps[e * 8]);
  }
  #pragma unroll
  for (int i = 0; i < 2; ++i) {  // K tile 0
    int e = i * 256 + tid;
    int row = e >> 3, gs = (e & 7) ^ (row & 7);
    gld_lds16(kp + (size_t)row * 64 + gs * 8, &Ks[0][e * 8]);
  }
  #pragma unroll
  for (int i = 0; i < 2; ++i) {  // V^T tile 0
    int e = i * 256 + tid;
    int row = e >> 3, gs = (e & 7) ^ (row & 7);
    gld_lds16(vp + (size_t)row * 2048 + gs * 8, &Vs[e * 8]);
  }
  SWAIT("vmcnt(4)");   // Q staged (K0/V0 still in flight)
  wgbar();             // publish Q

  bf16x8 qf[2][2];  // [iq][ks]  B-operand: n=q, k=d
  #pragma unroll
  for (int iq = 0; iq < 2; ++iq)
    #pragma unroll
    for (int ks = 0; ks < 2; ++ks)
      qf[iq][ks] = *(const bf16x8*)&Ps[(w * 32 + iq * 16 + lrow) * 64 + ((ks * 4 + quad) ^ sw) * 8];
  // Ps reuse for P is wave-local (wave w reads/writes rows [w*32, w*32+32) only);
  // qf reads retire before the first QK MFMA consumes them -> no barrier needed.

  f32x4 o_acc[4][2];  // O^T: d = id*16+quad*4+r, q = iq*16+lrow
  #pragma unroll
  for (int id = 0; id < 4; ++id)
    #pragma unroll
    for (int iq = 0; iq < 2; ++iq)
      #pragma unroll
      for (int r = 0; r < 4; ++r) o_acc[id][iq][r] = 0.f;
  float lsum[2] = {0.f, 0.f};

  // steady-state loop invariant at top: outstanding vmem = KS(t):2 + VS(t):2
  for (int t = 0; t < 32; ++t) {
    unsigned short* Kc = &Ks[t & 1][0];
    unsigned short* Kn = &Ks[(t + 1) & 1][0];
    const int ktn = (t + 1) & 31;  // wrapped dummy prefetch at t=31 keeps counts uniform

    // mask z loads for tile t (consumed as MFMA C-init; compiler inserts the
    // counted vmcnt before first use, which also retires VS(t) -> B3 is safe)
    f32x4 z[4][2];
    #pragma unroll
    for (int ik = 0; ik < 4; ++ik)
      #pragma unroll
      for (int iq = 0; iq < 2; ++iq)
        z[ik][iq] = *(const f32x4*)(mp + (size_t)(iq * 16 + lrow) * 2048 + t * 64 + ik * 16 + quad * 4);

    SWAIT("vmcnt(10)");  // retire KS(t) (oldest 2 of {KS:2, VS:2, mask:8})
    wgbar();             // B1: Ks[cur] published; Ks[cur^1] reader-free

    #pragma unroll
    for (int i = 0; i < 2; ++i) {  // prefetch K tile t+1 (stays in flight across B3/B2)
      int e = i * 256 + tid;
      int row = e >> 3, gs = (e & 7) ^ (row & 7);
      gld_lds16(kp + (size_t)(ktn * 64 + row) * 64 + gs * 8, &Kn[e * 8]);
    }

    // S^T = K (Q*c)^T + mask*log2e
    #pragma unroll
    for (int ks = 0; ks < 2; ++ks) {
      bf16x8 kf[4];
      const int g = ((ks * 4 + quad) ^ sw) * 8;
      #pragma unroll
      for (int ik = 0; ik < 4; ++ik)
        kf[ik] = *(const bf16x8*)&Kc[(ik * 16 + lrow) * 64 + g];
      #pragma unroll
      for (int ik = 0; ik < 4; ++ik)
        #pragma unroll
        for (int iq = 0; iq < 2; ++iq)
          z[ik][iq] = __builtin_amdgcn_mfma_f32_16x16x32_bf16(kf[ik], qf[iq][ks], z[ik][iq], 0, 0, 0);
    }

    // exp2, l partials, pack P -> wave-private swizzled Ps (pitch 64)
    #pragma unroll
    for (int ik = 0; ik < 4; ++ik)
      #pragma unroll
      for (int iq = 0; iq < 2; ++iq) {
        float e0 = exp2f(z[ik][iq][0]), e1 = exp2f(z[ik][iq][1]);
        float e2 = exp2f(z[ik][iq][2]), e3 = exp2f(z[ik][iq][3]);
        lsum[iq] += (e0 + e1) + (e2 + e3);
        uint2 p;
        p.x = pk_bf16(e0, e1);
        p.y = pk_bf16(e2, e3);
        // P[q][k], k0 = ik*16+quad*4: granule (k0>>3)^sw, 8B half (quad&1)
        *(uint2*)&Ps[(w * 32 + iq * 16 + lrow) * 64 +
                     ((ik * 2 + (quad >> 1)) ^ sw) * 8 + (quad & 1) * 4] = p;
      }
    SWAIT("lgkmcnt(0)");  // own Ps writes -> own reads
    wgbar();              // B3: publish Vs (every wave retired VS(t) at its z-wait)

    // O^T += V^T P^T
    #pragma unroll
    for (int ks = 0; ks < 2; ++ks) {
      bf16x8 vf[4], pf[2];
      const int g = ((ks * 4 + quad) ^ sw) * 8;
      #pragma unroll
      for (int id = 0; id < 4; ++id)
        vf[id] = *(const bf16x8*)&Vs[(id * 16 + lrow) * 64 + g];
      #pragma unroll
      for (int iq = 0; iq < 2; ++iq)
        pf[iq] = *(const bf16x8*)&Ps[(w * 32 + iq * 16 + lrow) * 64 + g];
      #pragma unroll
      for (int id = 0; id < 4; ++id)
        #pragma unroll
        for (int iq = 0; iq < 2; ++iq)
          o_acc[id][iq] = __builtin_amdgcn_mfma_f32_16x16x32_bf16(vf[id], pf[iq], o_acc[id][iq], 0, 0, 0);
    }

    wgbar();  // B2: all waves done reading Vs (KS(t+1) still in flight)

    #pragma unroll
    for (int i = 0; i < 2; ++i) {  // late-issue V tile t+1 (consumed after next QK+softmax)
      int e = i * 256 + tid;
      int row = e >> 3, gs = (e & 7) ^ (row & 7);
      gld_lds16(vp + (size_t)row * 2048 + ktn * 64 + gs * 8, &Vs[e * 8]);
    }
  }

  // normalize + store O^T
  unsigned short* ob = vals + (size_t)(b * 2048 + qt * 128 + w * 32) * 1024 + h * 64;
  #pragma unroll
  for (int iq = 0; iq < 2; ++iq) {
    float s = lsum[iq];
    s += __shfl_xor(s, 16);
    s += __shfl_xor(s, 32);
    float inv = 1.f / s;
    #pragma unroll
    for (int id = 0; id < 4; ++id) {
      uint2 p;
      p.x = pk_bf16(o_acc[id][iq][0] * inv, o_acc[id][iq][1] * inv);
      p.y = pk_bf16(o_acc[id][iq][2] * inv, o_acc[id][iq][3] * inv);
      *(uint2*)&ob[(size_t)(iq * 16 + lrow) * 1024 + id * 16 + quad * 4] = p;
    }
  }
}

extern "C" void kernel_launch(void* const* d_in, const int* in_sizes, int n_in,
                              void* d_out, int out_size, void* d_ws, size_t ws_size,
                              hipStream_t stream) {
  const float* x    = (const float*)d_in[0];
  const float* y    = (const float*)d_in[1];
  const float* mask = (const float*)d_in[2];
  const float* Wkv  = (const float*)d_in[3];
  const float* bkv  = (const float*)d_in[4];
  const float* Wq   = (const float*)d_in[5];
  const float* bq   = (const float*)d_in[6];
  const float* Wo   = (const float*)d_in[7];
  const float* bo   = (const float*)d_in[8];

  char* ws = (char*)d_ws;
  unsigned short* xb    = (unsigned short*)(ws + ((size_t)0 << 20));
  unsigned short* yb    = (unsigned short*)(ws + ((size_t)16 << 20));
  unsigned short* wkvt  = (unsigned short*)(ws + ((size_t)32 << 20));
  unsigned short* wqt   = (unsigned short*)(ws + ((size_t)36 << 20));
  unsigned short* wot   = (unsigned short*)(ws + ((size_t)38 << 20));
  unsigned short* kbuf  = (unsigned short*)(ws + ((size_t)40 << 20));
  unsigned short* vtbuf = (unsigned short*)(ws + ((size_t)56 << 20));
  unsigned short* qbuf  = (unsigned short*)(ws + ((size_t)72 << 20));
  unsigned short* valsb = (unsigned short*)(ws + ((size_t)88 << 20));
  float*          masks = (float*)        (ws + ((size_t)108 << 20));

  cast_xy<<<16384, 256, 0, stream>>>(x, y, xb, yb);
  scale_mask<<<4096, 256, 0, stream>>>(mask, masks);
  transpose_cast_all<<<4096, 256, 0, stream>>>(Wkv, Wq, Wo, wkvt, wqt, wot);

  // kv = x @ Wkv + bkv -> K[b,h,s,64], Vt[b,h,64,s]
  gemm128<1><<<dim3(16, 64), 256, 0, stream>>>(xb, wkvt, bkv, kbuf, vtbuf, 8192, 2048, 1024);
  // q = y @ Wq + bq -> Q[b,h,s,64] (pre-scaled)
  gemm128<2><<<dim3(8, 64), 256, 0, stream>>>(yb, wqt, bq, qbuf, nullptr, 8192, 1024, 1024);
  // attention -> vals [b,s,1024] bf16
  attn<<<1024, 256, 0, stream>>>(qbuf, kbuf, vtbuf, masks, valsb);
  // out = vals @ Wo + bo (fp32)
  gemm128<0><<<dim3(8, 64), 256, 0, stream>>>(valsb, wot, bo, (float*)d_out, nullptr, 8192, 1024, 1024);
}